// Round 5
// baseline (13262.265 us; speedup 1.0000x reference)
//
#include <hip/hip_runtime.h>
#include <math.h>

typedef _Float16 f16;
typedef _Float16 f16x8 __attribute__((ext_vector_type(8)));
typedef _Float16 f16x4 __attribute__((ext_vector_type(4)));
typedef float f32x4 __attribute__((ext_vector_type(4)));

#define B_ 32
#define T_ 1024
#define I_ 128
#define H_ 512
#define NWG 512
#define THR 512

// ---- workspace layout (bytes) ----
// control block (memset 20480 each call)
#define C_CNT8  0UL        // 8 x 64B per-XCD rank counters
#define C_DEC   512UL      // decision word
#define C_L1P   576UL      // layer-1 progress (sc1)
#define C_CTRF0 1024UL     // 32 x 64B fast counters, L0
#define C_CTRF1 3072UL     // fast counters, L1
#define C_CTRS0 5120UL     // 32 x 64B sc1 counters, L0 (fallback)
#define C_CTRS1 7168UL     // sc1 counters, L1 (fallback)
#define C_XCTR  9216UL     // 32 x 64B L0->L1 stream progress (sc1)
#define C_PROBE 11264UL    // 64 x 64B probe canary cells
#define C_MCTR  15360UL    // 64 x 64B probe rendezvous cells (ends 19456)
#define OFF_H1L 32768UL              // f16 [1025][32][512] = 33,587,200 (intra-L0 h1 seq)
#define OFF_H2S 33619968UL           // f16 [1025][32][512] = 33,587,200 (L1 h2 seq + FC input)
#define OFF_H1X 67207168UL           // f16 [64][32][512]   =  2,097,152 (cross-XCD h1 ring, sc1)
#define OFF_XT  69304320UL           // f16 [1024][32][128] =  8,388,608
// total 77,692,928 B

// gate buffer geometry (round-2 proven)
#define GS  68
#define GKH 2176
#define G16 1088

__device__ inline f32x4 mfma16(f16x8 a, f16x8 b, f32x4 c) {
  return __builtin_amdgcn_mfma_f32_16x16x32_f16(a, b, c, 0, 0, 0);
}
__device__ inline float fast_sig(float x) { return 1.f / (1.f + __expf(-x)); }
__device__ inline float fast_tanh(float x) {
  float e = __expf(-2.f * fabsf(x));
  float t = (1.f - e) / (1.f + e);
  return x < 0.f ? -t : t;
}

// ---- primitives ----
// sc1 (MALL/device scope) — proven in rounds 1-2
__device__ inline unsigned ld_sc1_u32(const unsigned* p) {
  unsigned r;
  asm volatile("global_load_dword %0, %1, off sc1\n\ts_waitcnt vmcnt(0)"
               : "=v"(r) : "v"(p) : "memory");
  return r;
}
__device__ inline void st_sc1_u32(unsigned* p, unsigned v) {
  asm volatile("global_store_dword %0, %1, off sc1" :: "v"(p), "v"(v) : "memory");
}
__device__ inline void st_sc1_u16(unsigned short* p, unsigned v) {
  asm volatile("global_store_short %0, %1, off sc1" :: "v"(p), "v"(v) : "memory");
}
// local-L2 atomics: always executed in L2 (never L1) -> fresh every poll
__device__ inline unsigned atomic_add0_local(unsigned* p) {
  unsigned old, zero = 0;
  asm volatile("global_atomic_add %0, %1, %2, off sc0\n\ts_waitcnt vmcnt(0)"
               : "=v"(old) : "v"(p), "v"(zero) : "memory");
  return old;
}
__device__ inline void atomic_swap_local(unsigned* p, unsigned v) {
  asm volatile("global_atomic_swap %0, %1, off" :: "v"(p), "v"(v) : "memory");
}
__device__ inline void wait_vm0() {
  asm volatile("s_waitcnt vmcnt(0)" ::: "memory");
  __builtin_amdgcn_sched_barrier(0);
}
// batched sc1 16B loads with in-asm drain (no async-output hazard)
__device__ inline void ld_sc1_b128x4(const int4* p0, const int4* p1,
                                     const int4* p2, const int4* p3,
                                     int4& a0, int4& a1, int4& a2, int4& a3) {
  asm volatile(
      "global_load_dwordx4 %0, %4, off sc1\n\t"
      "global_load_dwordx4 %1, %5, off sc1\n\t"
      "global_load_dwordx4 %2, %6, off sc1\n\t"
      "global_load_dwordx4 %3, %7, off sc1\n\t"
      "s_waitcnt vmcnt(0)"
      : "=&v"(a0), "=&v"(a1), "=&v"(a2), "=&v"(a3)
      : "v"(p0), "v"(p1), "v"(p2), "v"(p3) : "memory");
}
// bounded 64-cell sc1 rendezvous poll
__device__ inline void poll64_sc1_ge(const unsigned* base, unsigned tgt, int lane) {
  for (int it = 0; it < (1 << 22); ++it) {
    unsigned v = ld_sc1_u32(base + lane * 16);
    if (__all((int)(v >= tgt))) return;
    __builtin_amdgcn_s_sleep(2);
  }
}

// LDS XOR-swizzle (round-2 proven)
__device__ inline int swz_h(int b, int kbyte) { return b * 1024 + (kbyte ^ ((b & 7) << 4)); }
__device__ inline int swz_x(int b, int kbyte) { return b * 256  + (kbyte ^ ((b & 7) << 4)); }

// x[b][t][i] f32 -> xT[t][b][i] f16
__global__ __launch_bounds__(256) void prep_xT(const float* __restrict__ x, f16* __restrict__ xT) {
  const int idx = blockIdx.x * 256 + threadIdx.x;
  const int n4 = B_ * T_ * I_ / 4;
  if (idx < n4) {
    const int i4 = idx * 4;
    const int i  = i4 & (I_ - 1);
    const int tt = (i4 >> 7) & (T_ - 1);
    const int b  = i4 >> 17;
    float4 v = *(const float4*)(x + i4);
    f16x4 o;
    o[0] = (f16)v.x; o[1] = (f16)v.y; o[2] = (f16)v.z; o[3] = (f16)v.w;
    *(f16x4*)(xT + ((size_t)tt * B_ + b) * I_ + i) = o;
  }
}

__global__ __launch_bounds__(THR, 2) void lstm_persist(
    const float* __restrict__ Wih0, const float* __restrict__ Whh0,
    const float* __restrict__ bih0, const float* __restrict__ bhh0,
    const float* __restrict__ Wih1, const float* __restrict__ Whh1,
    const float* __restrict__ bih1, const float* __restrict__ bhh1,
    char* ws) {
  __shared__ int4 h1l4[2048];        // 32KB staged h1
  __shared__ int4 auxl4[2048];       // 32KB staged x (L0) / h2 (L1)
  __shared__ float gbuf[4352];       // 17KB gate partials [2][32][68]
  __shared__ float biasl[64];

  const int tid  = threadIdx.x;
  const int wgid = blockIdx.x;
  const int lane = tid & 63;
  const int wv   = tid >> 6;
  const int cfr  = lane & 15;
  const int ksub = lane >> 4;
  const int nt   = wv & 3;
  const int kh   = wv >> 2;
  const int rb   = tid >> 4;         // pointwise batch row
  const int hp   = tid & 15;         // pointwise col within 16

  unsigned* cnt8  = (unsigned*)(ws + C_CNT8);
  unsigned* dec   = (unsigned*)(ws + C_DEC);
  unsigned* l1pp  = (unsigned*)(ws + C_L1P);
  unsigned* xctr  = (unsigned*)(ws + C_XCTR);
  unsigned* probeC = (unsigned*)(ws + C_PROBE);
  unsigned* mctr  = (unsigned*)(ws + C_MCTR);
  int* shi = (int*)gbuf;

  // ---- 1. self-rank within own XCD (device-scope HIP atomics, m20-proven) ----
  if (tid == 0) {
    unsigned xcc = __builtin_amdgcn_s_getreg(6164) & 7u;   // HW_REG_XCC_ID
    unsigned rk = atomicAdd(cnt8 + xcc * 16, 1u);
    shi[0] = (int)xcc; shi[1] = (int)rk;
  }
  __syncthreads();
  const int myxcd = shi[0];
  const int myrank = shi[1];

  // ---- 2. leader picks the two first-full XCD clusters ----
  if (wgid == 0 && tid == 0) {
    unsigned enc = 0x80000000u;                            // default: wgid fallback
    for (int it = 0; it < (1 << 22); ++it) {
      int a = -1, b = -1;
      for (int x2 = 0; x2 < 8; ++x2) {
        unsigned c = atomicAdd(cnt8 + x2 * 16, 0u);
        if (c >= 32u) { if (a < 0) a = x2; else if (b < 0) b = x2; }
      }
      if (b >= 0) { enc = 0x80000000u | 0x100u | ((unsigned)a << 4) | (unsigned)b; break; }
      __builtin_amdgcn_s_sleep(8);
    }
    atomicExch(dec, enc);
  }
  if (tid == 0) {
    unsigned d = 0;
    for (int it = 0; it < (1 << 22); ++it) {
      d = atomicAdd(dec, 0u);
      if (d & 0x80000000u) break;
      __builtin_amdgcn_s_sleep(4);
    }
    if (!(d & 0x80000000u)) d = 0x80000000u;
    ((unsigned*)shi)[2] = d;
  }
  __syncthreads();
  const unsigned dv = ((unsigned*)shi)[2];
  __syncthreads();
  const bool cand = (dv & 0x100u) != 0;
  int role = -1, gid = 0;
  if (cand) {
    const int xa = (dv >> 4) & 0xF, xb = dv & 0xF;
    if (myxcd == xa && myrank < 32)      { role = 0; gid = myrank; }
    else if (myxcd == xb && myrank < 32) { role = 1; gid = myrank; }
  } else {
    if (wgid < 32)      { role = 0; gid = wgid; }
    else if (wgid < 64) { role = 1; gid = wgid - 32; }
  }
  if (role < 0) return;
  const int widx = role * 32 + gid;

  // ---- 3. probe: validate BOTH fast-path mechanisms within each group ----
  if (tid == 0) {
    *(volatile unsigned*)(probeC + widx * 16)     = 0xC0DE0000u + (unsigned)widx;
    *(volatile unsigned*)(probeC + widx * 16 + 8) = 0xFACE0000u + (unsigned)widx;
  }
  wait_vm0();
  __syncthreads();
  if (tid == 0) st_sc1_u32(mctr + widx * 16, 1u);
  poll64_sc1_ge(mctr, 1u, lane);
  int okv = 1;
  if (lane < 32) {
    const int j = role * 32 + lane;
    unsigned va = atomic_add0_local(probeC + j * 16);          // plain-store -> L2-atomic read
    unsigned vb = *(volatile unsigned*)(probeC + j * 16 + 8);  // plain-store -> plain cold read
    okv = (va == 0xC0DE0000u + (unsigned)j) && (vb == 0xFACE0000u + (unsigned)j);
  }
  okv = __all(okv);
  if (lane == 0) shi[8 + wv] = okv;
  __syncthreads();
  int grpok = 1;
#pragma unroll
  for (int w = 0; w < 8; ++w) grpok &= shi[8 + w];
  __syncthreads();
  if (tid == 0) st_sc1_u32(mctr + widx * 16, grpok ? 3u : 2u);
  poll64_sc1_ge(mctr, 2u, lane);
  int fok = 1;
  if (lane < 32) fok = (ld_sc1_u32(mctr + (role * 32 + lane) * 16) == 3u) ? 1 : 0;
  const bool fast = cand && (__all(fok) != 0);

  const char* h1c = (const char*)h1l4;
  const char* xc  = (const char*)auxl4;
  const char* h2c = (const char*)auxl4;
  unsigned short* h1l = (unsigned short*)(ws + OFF_H1L);
  unsigned short* h2s = (unsigned short*)(ws + OFF_H2S);
  unsigned short* h1x = (unsigned short*)(ws + OFF_H1X);

  if (role == 0) {
    // ================= layer 0 =================
    if (tid < 64) {
      const int row = (tid >> 4) * 512 + gid * 16 + (tid & 15);
      biasl[tid] = bih0[row] + bhh0[row];
    }
    f16x8 wa[10];
    {
      const int wrow = nt * 512 + gid * 16 + cfr;
#pragma unroll
      for (int ksl = 0; ksl < 10; ++ksl) {
        const int k = (kh * 10 + ksl) * 32 + ksub * 8;
        const float* src = (k < I_) ? (Wih0 + (size_t)wrow * I_ + k)
                                    : (Whh0 + (size_t)wrow * H_ + (k - I_));
        float4 v0 = *(const float4*)(src);
        float4 v1 = *(const float4*)(src + 4);
        f16x8 h;
        h[0]=(f16)v0.x; h[1]=(f16)v0.y; h[2]=(f16)v0.z; h[3]=(f16)v0.w;
        h[4]=(f16)v1.x; h[5]=(f16)v1.y; h[6]=(f16)v1.z; h[7]=(f16)v1.w;
        wa[ksl] = h;
      }
    }
    unsigned* ctrF = (unsigned*)(ws + C_CTRF0);
    unsigned* ctrS = (unsigned*)(ws + C_CTRS0);
    float cst = 0.f;
    unsigned short hkeep = 0;
    unsigned cs = 0, lp = 0;
    bool dead = false;
    __syncthreads();

    for (int s = 0; s < T_; ++s) {
      const int4 xv = ((const int4*)(ws + OFF_XT))[(size_t)s * 512 + tid];
      if (s >= 1 && !dead) {
        const unsigned tgt = (unsigned)s;
        int it = 0;
        for (;;) {
          int ok = 1;
          if (lane < 32) {
            if (cs < tgt) cs = fast ? atomic_add0_local(ctrF + lane * 16)
                                    : ld_sc1_u32(ctrS + lane * 16);
            ok = (cs >= tgt) ? 1 : 0;
          } else if (lane == 32) {
            if ((unsigned)s > lp + 48u) lp = ld_sc1_u32(l1pp);
            ok = ((unsigned)s <= lp + 48u) ? 1 : 0;
          }
          if (__all(ok)) break;
          if (++it > (1 << 17)) { dead = true; break; }
          __builtin_amdgcn_s_sleep(1);
        }
        if (lane < 32) cs = tgt;
      }
      // stage h1[s-1] from H1L slot s (write-once; plain cold loads)
      {
        const int4* src = (const int4*)h1l + (size_t)s * 2048;
#pragma unroll
        for (int r = 0; r < 4; ++r) {
          const int u = r * 512 + tid;
          int4 v = src[u];
          *(int4*)((char*)h1l4 + swz_h(u >> 6, (u & 63) * 16)) = v;
        }
      }
      *(int4*)((char*)auxl4 + swz_x(tid >> 4, (tid & 15) * 16)) = xv;
      __syncthreads();
      // deferred cross-XCD stream store of h1[s-1] (drains under MFMA)
      if (s >= 1)
        st_sc1_u16(h1x + (size_t)(s & 63) * 16384 + rb * 512 + gid * 16 + hp, hkeep);
      // MFMA: gates[s] = [x_s | h1_{s-1}] @ W0^T
      f32x4 a0 = {0.f,0.f,0.f,0.f}, a1 = {0.f,0.f,0.f,0.f};
#pragma unroll
      for (int ksl = 0; ksl < 10; ++ksl) {
        const int k = (kh * 10 + ksl) * 32 + ksub * 8;
        f16x8 af0, af1;
        if (k < I_) {
          af0 = *(const f16x8*)(xc + swz_x(cfr,      k * 2));
          af1 = *(const f16x8*)(xc + swz_x(16 + cfr, k * 2));
        } else {
          af0 = *(const f16x8*)(h1c + swz_h(cfr,      (k - I_) * 2));
          af1 = *(const f16x8*)(h1c + swz_h(16 + cfr, (k - I_) * 2));
        }
        a0 = mfma16(af0, wa[ksl], a0);
        a1 = mfma16(af1, wa[ksl], a1);
      }
      {
        const int base = kh * GKH + (ksub * 4) * GS + nt * 16 + cfr;
#pragma unroll
        for (int r = 0; r < 4; ++r) {
          gbuf[base + r * GS]       = a0[r];
          gbuf[base + G16 + r * GS] = a1[r];
        }
      }
      __syncthreads();
      // pointwise
      {
        const float* gr = gbuf + rb * GS;
        const float pi = gr[hp]      + gr[GKH + hp]      + biasl[hp];
        const float pf = gr[16 + hp] + gr[GKH + 16 + hp] + biasl[16 + hp];
        const float pg = gr[32 + hp] + gr[GKH + 32 + hp] + biasl[32 + hp];
        const float po = gr[48 + hp] + gr[GKH + 48 + hp] + biasl[48 + hp];
        const float ig = fast_sig(pi), fg = fast_sig(pf);
        const float gg = fast_tanh(pg), og = fast_sig(po);
        cst = fg * cst + ig * gg;
        const float hv = og * fast_tanh(cst);
        const f16 hf = (f16)hv;
        const unsigned short hbits = __builtin_bit_cast(unsigned short, hf);
        unsigned short* dst = h1l + (size_t)(s + 1) * 16384 + rb * 512 + gid * 16 + hp;
        if (fast) *(volatile unsigned short*)dst = hbits;
        else      st_sc1_u16(dst, hbits);
        hkeep = hbits;
      }
      wait_vm0();
      __syncthreads();
      if (tid == 0) {
        if (fast) atomic_swap_local(ctrF + gid * 16, (unsigned)(s + 1));
        else      st_sc1_u32(ctrS + gid * 16, (unsigned)(s + 1));
        st_sc1_u32(xctr + gid * 16, (unsigned)s);
      }
    }
    // epilogue: flush final h1[T-1] to the stream, publish xctr = T
    st_sc1_u16(h1x + (size_t)(T_ & 63) * 16384 + rb * 512 + gid * 16 + hp, hkeep);
    wait_vm0();
    __syncthreads();
    if (tid == 0) st_sc1_u32(xctr + gid * 16, (unsigned)T_);

  } else {
    // ================= layer 1 (lags L0 via the sc1 stream) =================
    if (tid < 64) {
      const int row = (tid >> 4) * 512 + gid * 16 + (tid & 15);
      biasl[tid] = bih1[row] + bhh1[row];
    }
    f16x8 wb[16];
    {
      const int wrow = nt * 512 + gid * 16 + cfr;
#pragma unroll
      for (int ksl = 0; ksl < 16; ++ksl) {
        const int k = (kh * 16 + ksl) * 32 + ksub * 8;
        const float* src = (k < H_) ? (Wih1 + (size_t)wrow * H_ + k)
                                    : (Whh1 + (size_t)wrow * H_ + (k - H_));
        float4 v0 = *(const float4*)(src);
        float4 v1 = *(const float4*)(src + 4);
        f16x8 h;
        h[0]=(f16)v0.x; h[1]=(f16)v0.y; h[2]=(f16)v0.z; h[3]=(f16)v0.w;
        h[4]=(f16)v1.x; h[5]=(f16)v1.y; h[6]=(f16)v1.z; h[7]=(f16)v1.w;
        wb[ksl] = h;
      }
    }
    unsigned* ctrF = (unsigned*)(ws + C_CTRF1);
    unsigned* ctrS = (unsigned*)(ws + C_CTRS1);
    float cst = 0.f;
    unsigned cs = 0, xs = 0;
    bool dead = false;
    __syncthreads();

    for (int t = 0; t < T_; ++t) {
      if (!dead) {
        const unsigned tgtA = (unsigned)t, tgtB = (unsigned)(t + 1);
        int it = 0;
        for (;;) {
          int ok = 1;
          if (lane < 32) {
            if (cs < tgtA) cs = fast ? atomic_add0_local(ctrF + lane * 16)
                                     : ld_sc1_u32(ctrS + lane * 16);
            ok = (cs >= tgtA) ? 1 : 0;
          } else {
            if (xs < tgtB) xs = ld_sc1_u32(xctr + (lane - 32) * 16);
            ok = (xs >= tgtB) ? 1 : 0;
          }
          if (__all(ok)) break;
          if (++it > (1 << 17)) { dead = true; break; }
          __builtin_amdgcn_s_sleep(1);
        }
        if (lane < 32) cs = tgtA;
      }
      // stage h2[t-1] from H2S slot t (write-once; plain loads)
      {
        const int4* src = (const int4*)h2s + (size_t)t * 2048;
#pragma unroll
        for (int r = 0; r < 4; ++r) {
          const int u = r * 512 + tid;
          int4 v = src[u];
          *(int4*)((char*)auxl4 + swz_h(u >> 6, (u & 63) * 16)) = v;
        }
      }
      // stage h1[t] from H1X ring slot (t+1)&63 via sc1 loads (guaranteed fresh)
      {
        const int4* base = (const int4*)(h1x + (size_t)((t + 1) & 63) * 16384);
        int4 a0, a1, a2, a3;
        ld_sc1_b128x4(base + tid, base + 512 + tid, base + 1024 + tid, base + 1536 + tid,
                      a0, a1, a2, a3);
        { const int u = tid;        *(int4*)((char*)h1l4 + swz_h(u >> 6, (u & 63) * 16)) = a0; }
        { const int u = 512 + tid;  *(int4*)((char*)h1l4 + swz_h(u >> 6, (u & 63) * 16)) = a1; }
        { const int u = 1024 + tid; *(int4*)((char*)h1l4 + swz_h(u >> 6, (u & 63) * 16)) = a2; }
        { const int u = 1536 + tid; *(int4*)((char*)h1l4 + swz_h(u >> 6, (u & 63) * 16)) = a3; }
      }
      __syncthreads();
      // MFMA: gates[t] = [h1_t | h2_{t-1}] @ W1^T
      f32x4 a0 = {0.f,0.f,0.f,0.f}, a1 = {0.f,0.f,0.f,0.f};
#pragma unroll
      for (int ksl = 0; ksl < 16; ++ksl) {
        const int k = (kh * 16 + ksl) * 32 + ksub * 8;
        f16x8 af0, af1;
        if (k < H_) {
          af0 = *(const f16x8*)(h1c + swz_h(cfr,      k * 2));
          af1 = *(const f16x8*)(h1c + swz_h(16 + cfr, k * 2));
        } else {
          af0 = *(const f16x8*)(h2c + swz_h(cfr,      (k - H_) * 2));
          af1 = *(const f16x8*)(h2c + swz_h(16 + cfr, (k - H_) * 2));
        }
        a0 = mfma16(af0, wb[ksl], a0);
        a1 = mfma16(af1, wb[ksl], a1);
      }
      {
        const int base = kh * GKH + (ksub * 4) * GS + nt * 16 + cfr;
#pragma unroll
        for (int r = 0; r < 4; ++r) {
          gbuf[base + r * GS]       = a0[r];
          gbuf[base + G16 + r * GS] = a1[r];
        }
      }
      __syncthreads();
      // pointwise -> h2[t] into H2S slot t+1
      {
        const float* gr = gbuf + rb * GS;
        const float pi = gr[hp]      + gr[GKH + hp]      + biasl[hp];
        const float pf = gr[16 + hp] + gr[GKH + 16 + hp] + biasl[16 + hp];
        const float pg = gr[32 + hp] + gr[GKH + 32 + hp] + biasl[32 + hp];
        const float po = gr[48 + hp] + gr[GKH + 48 + hp] + biasl[48 + hp];
        const float ig = fast_sig(pi), fg = fast_sig(pf);
        const float gg = fast_tanh(pg), og = fast_sig(po);
        cst = fg * cst + ig * gg;
        const float hv = og * fast_tanh(cst);
        const f16 hf = (f16)hv;
        const unsigned short hbits = __builtin_bit_cast(unsigned short, hf);
        unsigned short* dst = h2s + (size_t)(t + 1) * 16384 + rb * 512 + gid * 16 + hp;
        if (fast) *(volatile unsigned short*)dst = hbits;
        else      st_sc1_u16(dst, hbits);
      }
      wait_vm0();
      __syncthreads();
      if (tid == 0) {
        if (fast) atomic_swap_local(ctrF + gid * 16, (unsigned)(t + 1));
        else      st_sc1_u32(ctrS + gid * 16, (unsigned)(t + 1));
        if (gid == 0) st_sc1_u32(l1pp, (unsigned)(t + 1));
      }
    }
  }
}

// fused FC1+FC2: out[b*1024+t] = ((h2[t*32+b] @ fcW^T + fcb) @ fc2W^T + fc2b)
__global__ __launch_bounds__(256) void fc_fused(const f16* __restrict__ h2rows,
                                                const float* __restrict__ fcW,
                                                const float* __restrict__ fcb,
                                                const float* __restrict__ fc2W,
                                                const float* __restrict__ fc2b,
                                                float* __restrict__ out) {
  __shared__ float hT[64][36];
  __shared__ float wT[128][36];
  __shared__ float oL[64][136];
  const int bt0 = blockIdx.x * 64;
  const int t = threadIdx.x;
  const int c4 = (t & 31) * 4;
  const int rowg = t >> 5;
  float acc[8][4];
#pragma unroll
  for (int r = 0; r < 8; ++r)
#pragma unroll
    for (int j = 0; j < 4; ++j) acc[r][j] = 0.f;

  for (int kc = 0; kc < 16; ++kc) {
    {
      const int r = t >> 2, q = t & 3;
      const f16x8 v = *(const f16x8*)(h2rows + (size_t)(bt0 + r) * 512 + kc * 32 + q * 8);
#pragma unroll
      for (int j = 0; j < 8; ++j) hT[r][q * 8 + j] = (float)v[j];
    }
#pragma unroll
    for (int u = t; u < 1024; u += 256) {
      const int cc = u >> 3, k4 = u & 7;
      *(float4*)&wT[cc][k4 * 4] = *(const float4*)(fcW + (size_t)cc * 512 + kc * 32 + k4 * 4);
    }
    __syncthreads();
#pragma unroll
    for (int k4 = 0; k4 < 8; ++k4) {
      float4 w0 = *(float4*)&wT[c4 + 0][k4 * 4];
      float4 w1 = *(float4*)&wT[c4 + 1][k4 * 4];
      float4 w2 = *(float4*)&wT[c4 + 2][k4 * 4];
      float4 w3 = *(float4*)&wT[c4 + 3][k4 * 4];
#pragma unroll
      for (int rr = 0; rr < 8; ++rr) {
        float4 h = *(float4*)&hT[rowg * 8 + rr][k4 * 4];
        acc[rr][0] += h.x * w0.x + h.y * w0.y + h.z * w0.z + h.w * w0.w;
        acc[rr][1] += h.x * w1.x + h.y * w1.y + h.z * w1.z + h.w * w1.w;
        acc[rr][2] += h.x * w2.x + h.y * w2.y + h.z * w2.z + h.w * w2.w;
        acc[rr][3] += h.x * w3.x + h.y * w3.y + h.z * w3.z + h.w * w3.w;
      }
    }
    __syncthreads();
  }
  // o1 tile -> LDS
#pragma unroll
  for (int rr = 0; rr < 8; ++rr)
#pragma unroll
    for (int j = 0; j < 4; ++j)
      oL[rowg * 8 + rr][c4 + j] = acc[rr][j] + fcb[c4 + j];
  __syncthreads();
  // FC2 from LDS
  float a2[8][4];
#pragma unroll
  for (int r = 0; r < 8; ++r)
#pragma unroll
    for (int j = 0; j < 4; ++j) a2[r][j] = 0.f;
#pragma unroll
  for (int k4 = 0; k4 < 32; ++k4) {
    float4 w0 = *(const float4*)(fc2W + (size_t)(c4 + 0) * 128 + k4 * 4);
    float4 w1 = *(const float4*)(fc2W + (size_t)(c4 + 1) * 128 + k4 * 4);
    float4 w2 = *(const float4*)(fc2W + (size_t)(c4 + 2) * 128 + k4 * 4);
    float4 w3 = *(const float4*)(fc2W + (size_t)(c4 + 3) * 128 + k4 * 4);
#pragma unroll
    for (int rr = 0; rr < 8; ++rr) {
      float4 h = *(float4*)&oL[rowg * 8 + rr][k4 * 4];
      a2[rr][0] += h.x * w0.x + h.y * w0.y + h.z * w0.z + h.w * w0.w;
      a2[rr][1] += h.x * w1.x + h.y * w1.y + h.z * w1.z + h.w * w1.w;
      a2[rr][2] += h.x * w2.x + h.y * w2.y + h.z * w2.z + h.w * w2.w;
      a2[rr][3] += h.x * w3.x + h.y * w3.y + h.z * w3.z + h.w * w3.w;
    }
  }
#pragma unroll
  for (int rr = 0; rr < 8; ++rr) {
    const int r = bt0 + rowg * 8 + rr;                 // r = t*32+b
    const int outrow = ((r & 31) << 10) | (r >> 5);    // b*1024+t
#pragma unroll
    for (int j = 0; j < 4; ++j)
      out[(size_t)outrow * 128 + c4 + j] = a2[rr][j] + fc2b[c4 + j];
  }
}

extern "C" void kernel_launch(void* const* d_in, const int* in_sizes, int n_in,
                              void* d_out, int out_size, void* d_ws, size_t ws_size,
                              hipStream_t stream) {
  (void)in_sizes; (void)n_in; (void)out_size; (void)ws_size;
  const float* x    = (const float*)d_in[0];
  const float* Wih0 = (const float*)d_in[1];
  const float* Whh0 = (const float*)d_in[2];
  const float* bih0 = (const float*)d_in[3];
  const float* bhh0 = (const float*)d_in[4];
  const float* Wih1 = (const float*)d_in[5];
  const float* Whh1 = (const float*)d_in[6];
  const float* bih1 = (const float*)d_in[7];
  const float* bhh1 = (const float*)d_in[8];
  const float* fcW  = (const float*)d_in[9];
  const float* fcb  = (const float*)d_in[10];
  const float* fc2W = (const float*)d_in[11];
  const float* fc2b = (const float*)d_in[12];

  char* ws = (char*)d_ws;
  f16* xT = (f16*)(ws + OFF_XT);
  const f16* h2rows = (const f16*)(ws + OFF_H2S) + 16384;  // skip slot 0
  float* out = (float*)d_out;

  // per-call init: control block + the three h[-1] zero slots
  hipMemsetAsync(ws, 0, 20480, stream);
  hipMemsetAsync(ws + OFF_H1L, 0, 32768, stream);
  hipMemsetAsync(ws + OFF_H2S, 0, 32768, stream);
  hipMemsetAsync(ws + OFF_H1X, 0, 32768, stream);

  prep_xT<<<4096, 256, 0, stream>>>(x, xT);
  lstm_persist<<<NWG, THR, 0, stream>>>(Wih0, Whh0, bih0, bhh0,
                                        Wih1, Whh1, bih1, bhh1, ws);
  fc_fused<<<512, 256, 0, stream>>>(h2rows, fcW, fcb, fc2W, fc2b, out);
}

// Round 6
// 5016.484 us; speedup vs baseline: 2.6437x; 2.6437x over previous
//
#include <hip/hip_runtime.h>
#include <math.h>

typedef _Float16 f16;
typedef _Float16 f16x8 __attribute__((ext_vector_type(8)));
typedef _Float16 f16x4 __attribute__((ext_vector_type(4)));
typedef _Float16 f16x2 __attribute__((ext_vector_type(2)));
typedef float f32x4 __attribute__((ext_vector_type(4)));

#define B_ 32
#define T_ 1024
#define I_ 128
#define H_ 512

#define NWG 32
#define THR 512

// ---- workspace layout (bytes) ----
// Exchange arrays are write-once, block-contiguous: slot k = h[t=k-1];
// within a slot: [wg 0..31][1KB block = 32 batch-rows x 16 cols f16].
#define OFF_FLAGS 0UL                 // 32 x 64B flags = 2048
#define OFF_H1S   4096UL              // [1025][32768] = 33,587,200
#define OFF_H2S   33591296UL          // [1025][32768] = 33,587,200
#define OFF_XT    67178496UL          // f16 [1024][32][128] = 8,388,608
// total 75,567,104 B

__device__ inline f32x4 mfma16(f16x8 a, f16x8 b, f32x4 c) {
  return __builtin_amdgcn_mfma_f32_16x16x32_f16(a, b, c, 0, 0, 0);
}
__device__ inline float fast_sig(float x) { return 1.f / (1.f + __expf(-x)); }
__device__ inline float fast_tanh(float x) {
  float e = __expf(-2.f * fabsf(x));
  float t = (1.f - e) / (1.f + e);
  return x < 0.f ? -t : t;
}

// sc1 = device-coherent (MALL) ops — R2-proven protocol primitives
__device__ inline unsigned ld_sc1_u32(const unsigned* p) {
  unsigned r;
  asm volatile("global_load_dword %0, %1, off sc1\n\ts_waitcnt vmcnt(0)"
               : "=v"(r) : "v"(p) : "memory");
  return r;
}
__device__ inline void st_sc1_u32(unsigned* p, unsigned v) {
  asm volatile("global_store_dword %0, %1, off sc1" :: "v"(p), "v"(v) : "memory");
}

// LDS XOR-swizzle (R2-proven; 2-way conflicts on MFMA reads)
__device__ inline int swz_h(int b, int kbyte) { return b * 1024 + (kbyte ^ ((b & 7) << 4)); }
__device__ inline int swz_x(int b, int kbyte) { return b * 256  + (kbyte ^ ((b & 7) << 4)); }

// x[b][t][i] f32 -> xT[t][b][i] f16
__global__ __launch_bounds__(256) void prep_xT(const float* __restrict__ x, f16* __restrict__ xT) {
  const int idx = blockIdx.x * 256 + threadIdx.x;
  const int n4 = B_ * T_ * I_ / 4;
  if (idx < n4) {
    const int i4 = idx * 4;
    const int i  = i4 & (I_ - 1);
    const int tt = (i4 >> 7) & (T_ - 1);
    const int b  = i4 >> 17;
    float4 v = *(const float4*)(x + i4);
    f16x4 o;
    o[0] = (f16)v.x; o[1] = (f16)v.y; o[2] = (f16)v.z; o[3] = (f16)v.w;
    *(f16x4*)(xT + ((size_t)tt * B_ + b) * I_ + i) = o;
  }
}

// Persistent merged 2-layer LSTM (R2 structure), block-contiguous exchange.
// Step s: L0 computes h1[s] (s<T), L1 computes h2[s-1] (s>=1).
// End of step s: store h1[s]->H1S slot s+1, h2[s-1]->H2S slot s, flag=s+1.
// Step s stages h1[s-1] (slot s) and h2[s-2] (slot s-1), gated by flag>=s.
__global__ __launch_bounds__(THR, 2) void lstm_persist(
    const float* __restrict__ Wih0, const float* __restrict__ Whh0,
    const float* __restrict__ bih0, const float* __restrict__ bhh0,
    const float* __restrict__ Wih1, const float* __restrict__ Whh1,
    const float* __restrict__ bih1, const float* __restrict__ bhh1,
    char* ws) {
  __shared__ int4 h1l4[2048];          // 32KB  h1[s-1] (swizzled)
  __shared__ int4 h2l4[2048];          // 32KB  h2[s-2] (swizzled)
  __shared__ int4 xl4[512];            // 8KB   x[s] (swizzled)
  __shared__ float g0[2 * 32 * 68];    // L0 gate partials [kh][32b][64c pad 68]
  __shared__ float g1[2 * 32 * 68];    // L1 gate partials
  __shared__ float bias0[64], bias1[64];

  const int tid  = threadIdx.x;
  const int wg   = blockIdx.x;
  const int lane = tid & 63;
  const int wv   = tid >> 6;
  const int nt   = wv & 3;
  const int kh   = wv >> 2;
  const int cfr  = lane & 15;
  const int ksub = lane >> 4;

  unsigned* flags = (unsigned*)(ws + OFF_FLAGS);
  const char* h1base = ws + OFF_H1S;
  const char* h2base = ws + OFF_H2S;

  if (tid < 64) {
    const int g = tid >> 4, hc = tid & 15;
    const int row = g * 512 + wg * 16 + hc;
    bias0[tid] = bih0[row] + bhh0[row];
    bias1[tid] = bih1[row] + bhh1[row];
  }

  // ---- weight preload into VGPRs (R2-identical) ----
  const int gc  = nt * 16 + cfr;
  const int row = (gc >> 4) * 512 + wg * 16 + (gc & 15);
  f16x8 wa[10];
#pragma unroll
  for (int ksl = 0; ksl < 10; ++ksl) {
    const int k = (kh * 10 + ksl) * 32 + ksub * 8;
    const float* src = (k < I_) ? (Wih0 + (size_t)row * I_ + k)
                                : (Whh0 + (size_t)row * H_ + (k - I_));
    float4 v0 = *(const float4*)(src);
    float4 v1 = *(const float4*)(src + 4);
    f16x8 h;
    h[0] = (f16)v0.x; h[1] = (f16)v0.y; h[2] = (f16)v0.z; h[3] = (f16)v0.w;
    h[4] = (f16)v1.x; h[5] = (f16)v1.y; h[6] = (f16)v1.z; h[7] = (f16)v1.w;
    wa[ksl] = h;
  }
  f16x8 wb[16];
#pragma unroll
  for (int ksl = 0; ksl < 16; ++ksl) {
    const int k = (kh * 16 + ksl) * 32 + ksub * 8;
    const float* src = (k < H_) ? (Wih1 + (size_t)row * H_ + k)
                                : (Whh1 + (size_t)row * H_ + (k - H_));
    float4 v0 = *(const float4*)(src);
    float4 v1 = *(const float4*)(src + 4);
    f16x8 h;
    h[0] = (f16)v0.x; h[1] = (f16)v0.y; h[2] = (f16)v0.z; h[3] = (f16)v0.w;
    h[4] = (f16)v1.x; h[5] = (f16)v1.y; h[6] = (f16)v1.z; h[7] = (f16)v1.w;
    wb[ksl] = h;
  }

  float cst0 = 0.f, cst1 = 0.f;        // L0 cell state (threads 0..255)
  float dst0 = 0.f, dst1 = 0.f;        // L1 cell state (threads 256..511)
  const char* h1c = (const char*)h1l4;
  const char* h2c = (const char*)h2l4;
  const char* xc  = (const char*)xl4;

  __syncthreads();

  for (int s = 0; s <= T_; ++s) {
    // prefetch x[s] (plain; independent of flag)
    int4 xv;
    const bool hasx = (s < T_);
    if (hasx) xv = ((const int4*)(ws + OFF_XT))[(size_t)s * 512 + tid];

    // ---- gate: flag >= s confirms h1[s-1] (slot s) and h2[s-2] (slot s-1) ----
    if (s >= 1) {
      if (tid < 64) {
        const unsigned tgt = (unsigned)s;
        const unsigned* fp = flags + (tid < NWG ? tid : 0) * 16;
        const bool active = tid < NWG;
        for (;;) {
          unsigned v = ld_sc1_u32(fp);
          if (!active) v = tgt;
          if (__all((int)(v >= tgt))) break;
          __builtin_amdgcn_s_sleep(1);
        }
      }
      __syncthreads();
    }

    // ---- stage phase: block-linear plain cold loads -> swizzled LDS ----
    {
      const int4* src = (const int4*)(h1base + (size_t)s * 32768);
#pragma unroll
      for (int r = 0; r < 4; ++r) {
        const int u = r * 512 + tid;
        int4 v = src[u];
        const int wgs = u >> 6, b = (u >> 1) & 31, half = u & 1;
        *(int4*)((char*)h1l4 + swz_h(b, wgs * 32 + half * 16)) = v;
      }
    }
    if (s >= 1) {
      const int4* src = (const int4*)(h2base + (size_t)(s - 1) * 32768);
#pragma unroll
      for (int r = 0; r < 4; ++r) {
        const int u = r * 512 + tid;
        int4 v = src[u];
        const int wgs = u >> 6, b = (u >> 1) & 31, half = u & 1;
        *(int4*)((char*)h2l4 + swz_h(b, wgs * 32 + half * 16)) = v;
      }
    }
    if (hasx) *(int4*)((char*)xl4 + swz_x(tid >> 4, (tid & 15) * 16)) = xv;
    __syncthreads();

    // ---- MFMA phase (R2-identical) ----
    if (s < T_) {                      // L0: h1[s] gates
      f32x4 a0 = {0.f, 0.f, 0.f, 0.f}, a1 = {0.f, 0.f, 0.f, 0.f};
#pragma unroll
      for (int ksl = 0; ksl < 10; ++ksl) {
        const int k = (kh * 10 + ksl) * 32 + ksub * 8;
        f16x8 af0, af1;
        if (k < I_) {
          af0 = *(const f16x8*)(xc + swz_x(cfr,      k * 2));
          af1 = *(const f16x8*)(xc + swz_x(16 + cfr, k * 2));
        } else {
          af0 = *(const f16x8*)(h1c + swz_h(cfr,      (k - I_) * 2));
          af1 = *(const f16x8*)(h1c + swz_h(16 + cfr, (k - I_) * 2));
        }
        a0 = mfma16(af0, wa[ksl], a0);
        a1 = mfma16(af1, wa[ksl], a1);
      }
      const int base = kh * 2176 + (ksub * 4) * 68 + nt * 16 + cfr;
#pragma unroll
      for (int r = 0; r < 4; ++r) {
        g0[base + r * 68]            = a0[r];
        g0[base + 16 * 68 + r * 68]  = a1[r];
      }
    }
    if (s >= 1) {                      // L1: h2[s-1] gates, input [h1[s-1] | h2[s-2]]
      f32x4 a0 = {0.f, 0.f, 0.f, 0.f}, a1 = {0.f, 0.f, 0.f, 0.f};
#pragma unroll
      for (int ksl = 0; ksl < 16; ++ksl) {
        const int k = (kh * 16 + ksl) * 32 + ksub * 8;
        f16x8 af0, af1;
        if (k < H_) {
          af0 = *(const f16x8*)(h1c + swz_h(cfr,      k * 2));
          af1 = *(const f16x8*)(h1c + swz_h(16 + cfr, k * 2));
        } else {
          af0 = *(const f16x8*)(h2c + swz_h(cfr,      (k - H_) * 2));
          af1 = *(const f16x8*)(h2c + swz_h(16 + cfr, (k - H_) * 2));
        }
        a0 = mfma16(af0, wb[ksl], a0);
        a1 = mfma16(af1, wb[ksl], a1);
      }
      const int base = kh * 2176 + (ksub * 4) * 68 + nt * 16 + cfr;
#pragma unroll
      for (int r = 0; r < 4; ++r) {
        g1[base + r * 68]            = a0[r];
        g1[base + 16 * 68 + r * 68]  = a1[r];
      }
    }
    __syncthreads();

    // ---- pointwise + coalesced block-contiguous sc1 store ----
    if (s < T_ && tid < 256) {         // L0 -> H1S slot s+1
      const int rb = tid >> 3, hp = tid & 7;
      const float* gr = g0 + rb * 68;
      float hv[2];
#pragma unroll
      for (int cc = 0; cc < 2; ++cc) {
        const int c = 2 * hp + cc;
        const float pi = gr[c]      + gr[2176 + c]      + bias0[c];
        const float pf = gr[16 + c] + gr[2176 + 16 + c] + bias0[16 + c];
        const float pg = gr[32 + c] + gr[2176 + 32 + c] + bias0[32 + c];
        const float po = gr[48 + c] + gr[2176 + 48 + c] + bias0[48 + c];
        const float ig = fast_sig(pi), fg = fast_sig(pf);
        const float gg = fast_tanh(pg), og = fast_sig(po);
        const float cprev = cc ? cst1 : cst0;
        const float cnew = fg * cprev + ig * gg;
        if (cc) cst1 = cnew; else cst0 = cnew;
        hv[cc] = og * fast_tanh(cnew);
      }
      f16x2 pk; pk[0] = (f16)hv[0]; pk[1] = (f16)hv[1];
      unsigned* dst = (unsigned*)(h1base + (size_t)(s + 1) * 32768 +
                                  (size_t)wg * 1024 + rb * 32 + hp * 4);
      st_sc1_u32(dst, __builtin_bit_cast(unsigned, pk));
    }
    if (s >= 1 && tid >= 256) {        // L1 -> H2S slot s
      const int t2 = tid - 256;
      const int rb = t2 >> 3, hp = t2 & 7;
      const float* gr = g1 + rb * 68;
      float hv[2];
#pragma unroll
      for (int cc = 0; cc < 2; ++cc) {
        const int c = 2 * hp + cc;
        const float pi = gr[c]      + gr[2176 + c]      + bias1[c];
        const float pf = gr[16 + c] + gr[2176 + 16 + c] + bias1[16 + c];
        const float pg = gr[32 + c] + gr[2176 + 32 + c] + bias1[32 + c];
        const float po = gr[48 + c] + gr[2176 + 48 + c] + bias1[48 + c];
        const float ig = fast_sig(pi), fg = fast_sig(pf);
        const float gg = fast_tanh(pg), og = fast_sig(po);
        const float cprev = cc ? dst1 : dst0;
        const float cnew = fg * cprev + ig * gg;
        if (cc) dst1 = cnew; else dst0 = cnew;
        hv[cc] = og * fast_tanh(cnew);
      }
      f16x2 pk; pk[0] = (f16)hv[0]; pk[1] = (f16)hv[1];
      unsigned* dst = (unsigned*)(h2base + (size_t)s * 32768 +
                                  (size_t)wg * 1024 + rb * 32 + hp * 4);
      st_sc1_u32(dst, __builtin_bit_cast(unsigned, pk));
    }

    // ---- publish: per-wave drain, barrier (=> all drained), one flag ----
    asm volatile("s_waitcnt vmcnt(0)" ::: "memory");
    __syncthreads();
    if (tid == 0) st_sc1_u32(flags + wg * 16, (unsigned)(s + 1));
    __builtin_amdgcn_sched_barrier(0);
  }
}

// fused FC1+FC2 reading block layout: rows are bt = b*1024 + t.
// o1 = h2[t][b][:] @ fcW^T + fcb ; out = o1 @ fc2W^T + fc2b
__global__ __launch_bounds__(256) void fc_fused(const char* __restrict__ ws_h2,
                                                const float* __restrict__ fcW,
                                                const float* __restrict__ fcb,
                                                const float* __restrict__ fc2W,
                                                const float* __restrict__ fc2b,
                                                float* __restrict__ out) {
  __shared__ float hT[64][36];
  __shared__ float wT[128][36];
  __shared__ float oL[64][136];
  const int bt0 = blockIdx.x * 64;
  const int b   = bt0 >> 10;           // batch (fixed per block)
  const int t0  = bt0 & 1023;
  const int t = threadIdx.x;
  const int c4 = (t & 31) * 4;
  const int rowg = t >> 5;
  float acc[8][4];
#pragma unroll
  for (int r = 0; r < 8; ++r)
#pragma unroll
    for (int j = 0; j < 4; ++j) acc[r][j] = 0.f;

  for (int kc = 0; kc < 16; ++kc) {
    {
      const int r = t >> 2, q = t & 3;
      const int c0 = kc * 32 + q * 8;
      const f16x8 v = *(const f16x8*)(ws_h2 + (size_t)(t0 + r + 1) * 32768 +
                                      (size_t)(c0 >> 4) * 1024 + b * 32 + (c0 & 15) * 2);
#pragma unroll
      for (int j = 0; j < 8; ++j) hT[r][q * 8 + j] = (float)v[j];
    }
#pragma unroll
    for (int u = t; u < 1024; u += 256) {
      const int cc = u >> 3, k4 = u & 7;
      *(float4*)&wT[cc][k4 * 4] = *(const float4*)(fcW + (size_t)cc * 512 + kc * 32 + k4 * 4);
    }
    __syncthreads();
#pragma unroll
    for (int k4 = 0; k4 < 8; ++k4) {
      float4 w0 = *(float4*)&wT[c4 + 0][k4 * 4];
      float4 w1 = *(float4*)&wT[c4 + 1][k4 * 4];
      float4 w2 = *(float4*)&wT[c4 + 2][k4 * 4];
      float4 w3 = *(float4*)&wT[c4 + 3][k4 * 4];
#pragma unroll
      for (int rr = 0; rr < 8; ++rr) {
        float4 h = *(float4*)&hT[rowg * 8 + rr][k4 * 4];
        acc[rr][0] += h.x * w0.x + h.y * w0.y + h.z * w0.z + h.w * w0.w;
        acc[rr][1] += h.x * w1.x + h.y * w1.y + h.z * w1.z + h.w * w1.w;
        acc[rr][2] += h.x * w2.x + h.y * w2.y + h.z * w2.z + h.w * w2.w;
        acc[rr][3] += h.x * w3.x + h.y * w3.y + h.z * w3.z + h.w * w3.w;
      }
    }
    __syncthreads();
  }
#pragma unroll
  for (int rr = 0; rr < 8; ++rr)
#pragma unroll
    for (int j = 0; j < 4; ++j)
      oL[rowg * 8 + rr][c4 + j] = acc[rr][j] + fcb[c4 + j];
  __syncthreads();
  float a2[8][4];
#pragma unroll
  for (int r = 0; r < 8; ++r)
#pragma unroll
    for (int j = 0; j < 4; ++j) a2[r][j] = 0.f;
#pragma unroll
  for (int k4 = 0; k4 < 32; ++k4) {
    float4 w0 = *(const float4*)(fc2W + (size_t)(c4 + 0) * 128 + k4 * 4);
    float4 w1 = *(const float4*)(fc2W + (size_t)(c4 + 1) * 128 + k4 * 4);
    float4 w2 = *(const float4*)(fc2W + (size_t)(c4 + 2) * 128 + k4 * 4);
    float4 w3 = *(const float4*)(fc2W + (size_t)(c4 + 3) * 128 + k4 * 4);
#pragma unroll
    for (int rr = 0; rr < 8; ++rr) {
      float4 h = *(float4*)&oL[rowg * 8 + rr][k4 * 4];
      a2[rr][0] += h.x * w0.x + h.y * w0.y + h.z * w0.z + h.w * w0.w;
      a2[rr][1] += h.x * w1.x + h.y * w1.y + h.z * w1.z + h.w * w1.w;
      a2[rr][2] += h.x * w2.x + h.y * w2.y + h.z * w2.z + h.w * w2.w;
      a2[rr][3] += h.x * w3.x + h.y * w3.y + h.z * w3.z + h.w * w3.w;
    }
  }
#pragma unroll
  for (int rr = 0; rr < 8; ++rr) {
    const int r = bt0 + rowg * 8 + rr;
#pragma unroll
    for (int j = 0; j < 4; ++j)
      out[(size_t)r * 128 + c4 + j] = a2[rr][j] + fc2b[c4 + j];
  }
}

extern "C" void kernel_launch(void* const* d_in, const int* in_sizes, int n_in,
                              void* d_out, int out_size, void* d_ws, size_t ws_size,
                              hipStream_t stream) {
  (void)in_sizes; (void)n_in; (void)out_size; (void)ws_size;
  const float* x    = (const float*)d_in[0];
  const float* Wih0 = (const float*)d_in[1];
  const float* Whh0 = (const float*)d_in[2];
  const float* bih0 = (const float*)d_in[3];
  const float* bhh0 = (const float*)d_in[4];
  const float* Wih1 = (const float*)d_in[5];
  const float* Whh1 = (const float*)d_in[6];
  const float* bih1 = (const float*)d_in[7];
  const float* bhh1 = (const float*)d_in[8];
  const float* fcW  = (const float*)d_in[9];
  const float* fcb  = (const float*)d_in[10];
  const float* fc2W = (const float*)d_in[11];
  const float* fc2b = (const float*)d_in[12];

  char* ws = (char*)d_ws;
  f16* xT = (f16*)(ws + OFF_XT);
  float* out = (float*)d_out;

  // per-call init: flags + zero slot-0 of both exchange arrays (h[-1] = 0)
  hipMemsetAsync(ws + OFF_FLAGS, 0, 2048, stream);
  hipMemsetAsync(ws + OFF_H1S, 0, 32768, stream);
  hipMemsetAsync(ws + OFF_H2S, 0, 32768, stream);

  prep_xT<<<4096, 256, 0, stream>>>(x, xT);
  lstm_persist<<<NWG, THR, 0, stream>>>(Wih0, Whh0, bih0, bhh0,
                                        Wih1, Whh1, bih1, bhh1, ws);
  fc_fused<<<512, 256, 0, stream>>>(ws + OFF_H2S, fcW, fcb, fc2W, fc2b, out);
}